// Round 1
// baseline (451.272 us; speedup 1.0000x reference)
//
#include <hip/hip_runtime.h>
#include <cstddef>

// ---------------- problem constants ----------------
// N = 100000 nodes, E = 1600000 edges, D = H = 64. All fp32.
// out = relu(GC2(relu(GC1(x))))  with  GC(h) = agg(h) @ Wrel^T + b + h @ Wroot^T
// agg(h)[i] = sum_{e: dst[e]==i} ew[e] * h[src[e]]

#define FDIM 64

static inline size_t align256(size_t x) { return (x + 255) & ~size_t(255); }

// ---------------- edge-index dtype detector ----------------
// If edge_index was delivered as int64 (little-endian), every odd int32 word of
// the first 2048 int64 entries is 0 (values < 2^31). If int32, odd words are
// random src ids in [0,100000) -> virtually impossible to all be 0.
__global__ void k_detect(const int* __restrict__ ei, int* __restrict__ flag) {
    __shared__ int any;
    if (threadIdx.x == 0) any = 0;
    __syncthreads();
    for (int k = threadIdx.x; k < 2048; k += 256) {
        if (ei[2 * k + 1] != 0) any = 1;   // benign race, writes only 1
    }
    __syncthreads();
    if (threadIdx.x == 0) *flag = (any == 0) ? 1 : 0;  // 1 => int64 layout
}

// ---------------- CSR build ----------------
__global__ void k_hist(const int* __restrict__ ei, int E, const int* __restrict__ flag,
                       int* __restrict__ deg) {
    int i = blockIdx.x * blockDim.x + threadIdx.x;
    if (i >= E) return;
    int sh = *flag;                                  // 0: int32, 1: int64 (low word)
    int d = ei[(size_t)(E + i) << sh];
    atomicAdd(&deg[d], 1);
}

// per-block (1024 elems) sums
__global__ void k_scanA(const int* __restrict__ deg, int n, int* __restrict__ bsum) {
    __shared__ int s[256];
    int t = threadIdx.x;
    int base = blockIdx.x * 1024 + t * 4;
    int sum = 0;
#pragma unroll
    for (int j = 0; j < 4; ++j) { int idx = base + j; if (idx < n) sum += deg[idx]; }
    s[t] = sum; __syncthreads();
    for (int off = 128; off > 0; off >>= 1) {
        if (t < off) s[t] += s[t + off];
        __syncthreads();
    }
    if (t == 0) bsum[blockIdx.x] = s[0];
}

// single-block exclusive scan over nb (<=128) block sums; also writes row_ptr[N]=E
__global__ void k_scanB(const int* __restrict__ bsum, int nb, int* __restrict__ boff,
                        int* __restrict__ row_ptr, int n, int E) {
    __shared__ int s[128];
    int t = threadIdx.x;
    int v = (t < nb) ? bsum[t] : 0;
    s[t] = v; __syncthreads();
    for (int off = 1; off < 128; off <<= 1) {
        int a = (t >= off) ? s[t - off] : 0;
        __syncthreads();
        s[t] += a;
        __syncthreads();
    }
    if (t < nb) boff[t] = s[t] - v;                  // exclusive
    if (t == 0) row_ptr[n] = E;
}

__global__ void k_scanC(const int* __restrict__ deg, int n, const int* __restrict__ boff,
                        int* __restrict__ row_ptr, int* __restrict__ cursor) {
    __shared__ int s[256];
    int t = threadIdx.x;
    int base = blockIdx.x * 1024 + t * 4;
    int v[4]; int sum = 0;
#pragma unroll
    for (int j = 0; j < 4; ++j) { int idx = base + j; v[j] = (idx < n) ? deg[idx] : 0; sum += v[j]; }
    s[t] = sum; __syncthreads();
    for (int off = 1; off < 256; off <<= 1) {
        int a = (t >= off) ? s[t - off] : 0;
        __syncthreads();
        s[t] += a;
        __syncthreads();
    }
    int run = boff[blockIdx.x] + s[t] - sum;         // exclusive prefix of first elem
#pragma unroll
    for (int j = 0; j < 4; ++j) {
        int idx = base + j;
        if (idx < n) { row_ptr[idx] = run; cursor[idx] = run; run += v[j]; }
    }
}

__global__ void k_scatter(const int* __restrict__ ei, const float* __restrict__ ew, int E,
                          const int* __restrict__ flag, int* __restrict__ cursor,
                          int* __restrict__ es, float* __restrict__ ewp) {
    int i = blockIdx.x * blockDim.x + threadIdx.x;
    if (i >= E) return;
    int sh = *flag;
    int s = ei[(size_t)i << sh];
    int d = ei[(size_t)(E + i) << sh];
    int pos = atomicAdd(&cursor[d], 1);
    es[pos] = s;
    ewp[pos] = ew[i];
}

// ---------------- aggregation: one wave per node, lane = feature ----------------
__global__ void k_agg(const float* __restrict__ h, const int* __restrict__ row_ptr,
                      const int* __restrict__ es, const float* __restrict__ ewp,
                      int n, float* __restrict__ agg) {
    int wid = (blockIdx.x * blockDim.x + threadIdx.x) >> 6;  // node
    int lane = threadIdx.x & 63;                             // feature
    if (wid >= n) return;
    int p = row_ptr[wid], e = row_ptr[wid + 1];
    float acc = 0.f;
    for (; p + 4 <= e; p += 4) {
        int s0 = es[p], s1 = es[p + 1], s2 = es[p + 2], s3 = es[p + 3];
        float w0 = ewp[p], w1 = ewp[p + 1], w2 = ewp[p + 2], w3 = ewp[p + 3];
        float v0 = h[s0 * FDIM + lane];
        float v1 = h[s1 * FDIM + lane];
        float v2 = h[s2 * FDIM + lane];
        float v3 = h[s3 * FDIM + lane];
        acc = fmaf(v0, w0, acc);
        acc = fmaf(v1, w1, acc);
        acc = fmaf(v2, w2, acc);
        acc = fmaf(v3, w3, acc);
    }
    for (; p < e; ++p) acc = fmaf(h[es[p] * FDIM + lane], ewp[p], acc);
    agg[wid * FDIM + lane] = acc;
}

// ---------------- dense: out = relu(agg@Wrel^T + b + h@Wroot^T) ----------------
// 64-node tile, K=128 (concat agg|h), weights+inputs transposed in LDS,
// 4x4 register micro-tile, float4 LDS reads (2-way bank aliasing = free).
__global__ void __launch_bounds__(256)
k_dense(const float* __restrict__ agg, const float* __restrict__ hroot,
        const float* __restrict__ wrel, const float* __restrict__ wroot,
        const float* __restrict__ bias, float* __restrict__ out, int n) {
    __shared__ float w_t[128][64];   // w_t[k][o]
    __shared__ float in_t[128][64];  // in_t[k][local node]
    int tid = threadIdx.x;
    int n0 = blockIdx.x * 64;

    // stage weights transposed: w_t[d][o] = wrel[o][d]; w_t[64+d][o] = wroot[o][d]
#pragma unroll
    for (int it = 0; it < 8; ++it) {
        int f = it * 256 + tid;                      // float4 id in [0,2048)
        const float* m = (f < 1024) ? wrel : wroot;
        int fl = (f < 1024) ? f : f - 1024;
        int o = fl >> 4, d0 = (fl & 15) << 2;
        float4 wv = *reinterpret_cast<const float4*>(&m[o * FDIM + d0]);
        int kb = (f < 1024) ? 0 : 64;
        w_t[kb + d0 + 0][o] = wv.x;
        w_t[kb + d0 + 1][o] = wv.y;
        w_t[kb + d0 + 2][o] = wv.z;
        w_t[kb + d0 + 3][o] = wv.w;
    }
    // stage inputs: per node 128 floats (agg: k 0..63, hroot: k 64..127)
#pragma unroll
    for (int it = 0; it < 8; ++it) {
        int f = it * 256 + tid;                      // float4 id in [0,2048)
        int nf = f >> 5, q = f & 31, k0 = q << 2;
        int node = n0 + nf;
        float4 v = make_float4(0.f, 0.f, 0.f, 0.f);
        if (node < n) {
            const float* sp = (k0 < 64) ? &agg[node * FDIM + k0]
                                        : &hroot[node * FDIM + (k0 - 64)];
            v = *reinterpret_cast<const float4*>(sp);
        }
        in_t[k0 + 0][nf] = v.x;
        in_t[k0 + 1][nf] = v.y;
        in_t[k0 + 2][nf] = v.z;
        in_t[k0 + 3][nf] = v.w;
    }
    __syncthreads();

    int tx = tid & 15, ty = tid >> 4;
    int o0 = tx * 4, nl0 = ty * 4;
    float acc[4][4];
#pragma unroll
    for (int i = 0; i < 4; ++i)
#pragma unroll
        for (int j = 0; j < 4; ++j) acc[i][j] = 0.f;

#pragma unroll 4
    for (int k = 0; k < 128; ++k) {
        float4 iv = *reinterpret_cast<const float4*>(&in_t[k][nl0]);
        float4 wv = *reinterpret_cast<const float4*>(&w_t[k][o0]);
        acc[0][0] = fmaf(iv.x, wv.x, acc[0][0]);
        acc[0][1] = fmaf(iv.x, wv.y, acc[0][1]);
        acc[0][2] = fmaf(iv.x, wv.z, acc[0][2]);
        acc[0][3] = fmaf(iv.x, wv.w, acc[0][3]);
        acc[1][0] = fmaf(iv.y, wv.x, acc[1][0]);
        acc[1][1] = fmaf(iv.y, wv.y, acc[1][1]);
        acc[1][2] = fmaf(iv.y, wv.z, acc[1][2]);
        acc[1][3] = fmaf(iv.y, wv.w, acc[1][3]);
        acc[2][0] = fmaf(iv.z, wv.x, acc[2][0]);
        acc[2][1] = fmaf(iv.z, wv.y, acc[2][1]);
        acc[2][2] = fmaf(iv.z, wv.z, acc[2][2]);
        acc[2][3] = fmaf(iv.z, wv.w, acc[2][3]);
        acc[3][0] = fmaf(iv.w, wv.x, acc[3][0]);
        acc[3][1] = fmaf(iv.w, wv.y, acc[3][1]);
        acc[3][2] = fmaf(iv.w, wv.z, acc[3][2]);
        acc[3][3] = fmaf(iv.w, wv.w, acc[3][3]);
    }

    float b0 = bias[o0 + 0], b1v = bias[o0 + 1], b2v = bias[o0 + 2], b3 = bias[o0 + 3];
#pragma unroll
    for (int i = 0; i < 4; ++i) {
        int node = n0 + nl0 + i;
        if (node < n) {
            float4 o4;
            o4.x = fmaxf(acc[i][0] + b0, 0.f);
            o4.y = fmaxf(acc[i][1] + b1v, 0.f);
            o4.z = fmaxf(acc[i][2] + b2v, 0.f);
            o4.w = fmaxf(acc[i][3] + b3, 0.f);
            *reinterpret_cast<float4*>(&out[node * FDIM + o0]) = o4;
        }
    }
}

// ---------------- launch ----------------
extern "C" void kernel_launch(void* const* d_in, const int* in_sizes, int n_in,
                              void* d_out, int out_size, void* d_ws, size_t ws_size,
                              hipStream_t stream) {
    const float* x      = (const float*)d_in[0];
    const int*   ei     = (const int*)d_in[1];
    const float* ew     = (const float*)d_in[2];
    const float* w1rel  = (const float*)d_in[3];
    const float* b1     = (const float*)d_in[4];
    const float* w1root = (const float*)d_in[5];
    const float* w2rel  = (const float*)d_in[6];
    const float* b2     = (const float*)d_in[7];
    const float* w2root = (const float*)d_in[8];
    float* out = (float*)d_out;

    int N = in_sizes[0] / FDIM;
    int E = in_sizes[2];

    // workspace carve (all 256B-aligned)
    char* w = (char*)d_ws;
    int* deg     = (int*)w;  w += align256((size_t)N * 4);
    int* row_ptr = (int*)w;  w += align256((size_t)(N + 1) * 4);
    int* cursor  = (int*)w;  w += align256((size_t)N * 4);
    int* bsum    = (int*)w;  w += align256(512);
    int* boff    = (int*)w;  w += align256(512);
    int* flag    = (int*)w;  w += align256(256);
    int* es      = (int*)w;  w += align256((size_t)E * 4);
    float* ewp   = (float*)w; w += align256((size_t)E * 4);
    float* aggb  = (float*)w; w += align256((size_t)N * FDIM * 4);
    float* h1    = (float*)w; w += align256((size_t)N * FDIM * 4);

    int nb = (N + 1023) / 1024;   // 98 for N=100000 (fits scanB's 128 slots)

    hipMemsetAsync(deg, 0, (size_t)N * sizeof(int), stream);
    k_detect<<<1, 256, 0, stream>>>(ei, flag);
    k_hist<<<(E + 255) / 256, 256, 0, stream>>>(ei, E, flag, deg);
    k_scanA<<<nb, 256, 0, stream>>>(deg, N, bsum);
    k_scanB<<<1, 128, 0, stream>>>(bsum, nb, boff, row_ptr, N, E);
    k_scanC<<<nb, 256, 0, stream>>>(deg, N, boff, row_ptr, cursor);
    k_scatter<<<(E + 255) / 256, 256, 0, stream>>>(ei, ew, E, flag, cursor, es, ewp);

    // layer 1
    k_agg<<<(N + 3) / 4, 256, 0, stream>>>(x, row_ptr, es, ewp, N, aggb);
    k_dense<<<(N + 63) / 64, 256, 0, stream>>>(aggb, x, w1rel, w1root, b1, h1, N);
    // layer 2
    k_agg<<<(N + 3) / 4, 256, 0, stream>>>(h1, row_ptr, es, ewp, N, aggb);
    k_dense<<<(N + 63) / 64, 256, 0, stream>>>(aggb, h1, w2rel, w2root, b2, out, N);
}